// Round 5
// baseline (569.454 us; speedup 1.0000x reference)
//
#include <hip/hip_runtime.h>

// Problem: out[b,:] = softmax_s( enc[b,s,:] . w2 ),  w2[k] = sum_h v[h]*W[h,2H+k].
// hidden/bias contributions are constant along s -> cancel under softmax(axis=1).
// HBM floor: read enc once = 64*512*1024*4 B = 134 MB (~20 us at measured 6.9 TB/s).
// Measured dur_us also contains ~165-170 us of harness reset (536 MB ws poison
// fill + input restore) visible as fillBufferAligned dispatches in rocprof.
// R4: wfold 16->64 blocks: 203.4 -> 199.0 us (parallelism-starved confirmed).
// R5: fuse softmax into scores via last-block-per-b (agent-scope atomics).

#define HID 1024
#define BB  64
#define SS  512
#define W3H 3072

// Native Clang ext-vector: accepted by __builtin_nontemporal_load (HIP's
// float4 struct is not).
typedef float floatx4 __attribute__((ext_vector_type(4)));

// Kernel A: w2[k] = sum_h v[h] * W[h*3072 + 2048 + k]; also zeroes the per-b
// arrival counters (runs before the fused kernel in stream order).
// 64 blocks x 1024 threads. Block b owns k in [16b,16b+16);
// thread = (hg = t>>4 in [0,64), kl = t&15); 16 h per thread, LDS tree-reduce.
__global__ __launch_bounds__(1024) void wfold_kernel(
        const float* __restrict__ W, const float* __restrict__ v,
        float* __restrict__ w2, unsigned* __restrict__ cnt) {
    if (threadIdx.x == 0) cnt[blockIdx.x] = 0u;   // 64 blocks == 64 counters
    __shared__ float part[64][16];
    const int kl = threadIdx.x & 15;
    const int hg = threadIdx.x >> 4;            // 0..63
    const int k  = blockIdx.x * 16 + kl;
    float acc = 0.0f;
    #pragma unroll
    for (int h = hg * 16; h < hg * 16 + 16; ++h)
        acc += v[h] * W[(size_t)h * W3H + 2 * HID + k];
    part[hg][kl] = acc;
    __syncthreads();
    for (int half = 32; half >= 1; half >>= 1) {
        if (hg < half) part[hg][kl] += part[hg + half][kl];
        __syncthreads();
    }
    if (threadIdx.x < 16) w2[k] = part[0][kl];
}

// Kernel B (fused): scores[r] = dot(enc[r,:], w2), one wave per row, nt loads.
// 128 blocks per b (4 rows/block); last-arriving block per b does the softmax.
__global__ __launch_bounds__(256) void scores_softmax_kernel(
        const floatx4* __restrict__ enc4, const floatx4* __restrict__ w24,
        float* __restrict__ scores, unsigned* __restrict__ cnt,
        float* __restrict__ out) {
    const int wave = threadIdx.x >> 6;
    const int lane = threadIdx.x & 63;
    const int r = blockIdx.x * 4 + wave;            // r in [0, 32768)
    const int b = blockIdx.x >> 7;                  // 128 blocks per b
    const floatx4* row = enc4 + (size_t)r * (HID / 4);
    float acc = 0.0f;
    #pragma unroll
    for (int i = 0; i < 4; ++i) {
        floatx4 e = __builtin_nontemporal_load(&row[i * 64 + lane]);
        floatx4 w = w24[i * 64 + lane];
        acc += e.x * w.x + e.y * w.y + e.z * w.z + e.w * w.w;
    }
    #pragma unroll
    for (int off = 32; off > 0; off >>= 1)
        acc += __shfl_down(acc, off);
    if (lane == 0) scores[r] = acc;

    // ---- arrival: last block of this b runs the softmax ----
    __shared__ int isLast;
    __syncthreads();                                // all scores stores issued
    if (threadIdx.x == 0) {
        unsigned old = __hip_atomic_fetch_add(&cnt[b], 1u,
                          __ATOMIC_ACQ_REL, __HIP_MEMORY_SCOPE_AGENT);
        isLast = (old == 127u);
    }
    __syncthreads();
    if (!isLast) return;

    // softmax over scores[b*512 .. b*512+511] with 256 threads (2 each).
    const int t = threadIdx.x;
    float s0 = __hip_atomic_load(&scores[b * SS + t],
                    __ATOMIC_RELAXED, __HIP_MEMORY_SCOPE_AGENT);
    float s1 = __hip_atomic_load(&scores[b * SS + 256 + t],
                    __ATOMIC_RELAXED, __HIP_MEMORY_SCOPE_AGENT);

    __shared__ float red[4];
    float m = fmaxf(s0, s1);
    #pragma unroll
    for (int off = 32; off > 0; off >>= 1)
        m = fmaxf(m, __shfl_down(m, off));
    if (lane == 0) red[wave] = m;
    __syncthreads();
    m = fmaxf(fmaxf(red[0], red[1]), fmaxf(red[2], red[3]));
    __syncthreads();

    float e0 = expf(s0 - m), e1 = expf(s1 - m);
    float s = e0 + e1;
    #pragma unroll
    for (int off = 32; off > 0; off >>= 1)
        s += __shfl_down(s, off);
    if (lane == 0) red[wave] = s;
    __syncthreads();
    float tot = red[0] + red[1] + red[2] + red[3];

    out[b * SS + t]       = e0 / tot;
    out[b * SS + 256 + t] = e1 / tot;
}

extern "C" void kernel_launch(void* const* d_in, const int* in_sizes, int n_in,
                              void* d_out, int out_size, void* d_ws, size_t ws_size,
                              hipStream_t stream) {
    // inputs: hidden [2,64,1024] (unused), encoder_outputs [64,512,1024],
    //         W [1024,3072], b [1024] (unused), v [1024]
    const float* enc = (const float*)d_in[1];
    const float* W   = (const float*)d_in[2];
    const float* v   = (const float*)d_in[4];
    float* out = (float*)d_out;

    float*    w2     = (float*)d_ws;          // 1024 floats
    float*    scores = w2 + HID;              // 32768 floats
    unsigned* cnt    = (unsigned*)(scores + BB * SS);  // 64 counters

    wfold_kernel<<<64, 1024, 0, stream>>>(W, v, w2, cnt);

    scores_softmax_kernel<<<(BB * SS) / 4, 256, 0, stream>>>(
        (const floatx4*)enc, (const floatx4*)w2, scores, cnt, out);
}

// Round 6
// 199.712 us; speedup vs baseline: 2.8514x; 2.8514x over previous
//
#include <hip/hip_runtime.h>

// Problem: out[b,:] = softmax_s( enc[b,s,:] . w2 ),  w2[k] = sum_h v[h]*W[h,2H+k].
// hidden/bias contributions are constant along s -> cancel under softmax(axis=1).
// HBM floor: read enc once = 64*512*1024*4 B = 134 MB (~20 us at measured 6.9 TB/s).
// Measured dur_us also contains ~165-170 us of harness reset (536 MB ws poison
// fill + input restore) visible as fillBufferAligned dispatches in rocprof.
// R4: wfold 16->64 blocks: 203.4 -> 199.0 us (parallelism-starved confirmed).
// R5 FAILED: last-block fused softmax w/ per-block agent-scope ACQ_REL atomics
//   -> 569 us. Kernel stalled (VALUBusy 0.8%, 172 GB/s): each acquire/release
//   implies L1/L2 invalidate + vmcnt(0) drain; 8192 of them serialize the
//   memory pipe. Do NOT use per-block device-scope sync on streaming kernels.
// R6: revert to R4 structure (best known: 199.0 us).

#define HID 1024
#define BB  64
#define SS  512
#define W3H 3072

// Native Clang ext-vector: accepted by __builtin_nontemporal_load (HIP's
// float4 struct is not).
typedef float floatx4 __attribute__((ext_vector_type(4)));

// Kernel A: w2[k] = sum_h v[h] * W[h*3072 + 2048 + k], no atomics/memset.
// 64 blocks x 1024 threads. Block b owns k in [16b,16b+16);
// thread = (hg = t>>4 in [0,64), kl = t&15); 16 h per thread, LDS tree-reduce.
__global__ __launch_bounds__(1024) void wfold_kernel(
        const float* __restrict__ W, const float* __restrict__ v,
        float* __restrict__ w2) {
    __shared__ float part[64][16];
    const int kl = threadIdx.x & 15;
    const int hg = threadIdx.x >> 4;            // 0..63
    const int k  = blockIdx.x * 16 + kl;
    float acc = 0.0f;
    #pragma unroll
    for (int h = hg * 16; h < hg * 16 + 16; ++h)
        acc += v[h] * W[(size_t)h * W3H + 2 * HID + k];
    part[hg][kl] = acc;
    __syncthreads();
    for (int half = 32; half >= 1; half >>= 1) {
        if (hg < half) part[hg][kl] += part[hg + half][kl];
        __syncthreads();
    }
    if (threadIdx.x < 16) w2[k] = part[0][kl];
}

// Kernel B: scores[r] = dot(enc[r,:], w2). One wave per row, 16B loads,
// nontemporal on enc (streamed once; keep caches for w2/scores).
__global__ __launch_bounds__(256) void scores_kernel(
        const floatx4* __restrict__ enc4, const floatx4* __restrict__ w24,
        float* __restrict__ scores) {
    const int wave = threadIdx.x >> 6;
    const int lane = threadIdx.x & 63;
    const int r = blockIdx.x * 4 + wave;            // r in [0, 32768)
    const floatx4* row = enc4 + (size_t)r * (HID / 4);
    float acc = 0.0f;
    #pragma unroll
    for (int i = 0; i < 4; ++i) {
        floatx4 e = __builtin_nontemporal_load(&row[i * 64 + lane]);
        floatx4 w = w24[i * 64 + lane];
        acc += e.x * w.x + e.y * w.y + e.z * w.z + e.w * w.w;
    }
    #pragma unroll
    for (int off = 32; off > 0; off >>= 1)
        acc += __shfl_down(acc, off);
    if (lane == 0) scores[r] = acc;
}

// Kernel C: per-b softmax over 512 scores. One block of 512 threads per b.
__global__ __launch_bounds__(512) void softmax_kernel(
        const float* __restrict__ scores, float* __restrict__ out) {
    __shared__ float red[8];
    const int b = blockIdx.x;
    const int t = threadIdx.x;
    const int wave = t >> 6, lane = t & 63;

    float x = scores[b * SS + t];

    float m = x;
    #pragma unroll
    for (int off = 32; off > 0; off >>= 1)
        m = fmaxf(m, __shfl_down(m, off));
    if (lane == 0) red[wave] = m;
    __syncthreads();
    if (t == 0) {
        float mm = red[0];
        #pragma unroll
        for (int i = 1; i < 8; ++i) mm = fmaxf(mm, red[i]);
        red[0] = mm;
    }
    __syncthreads();
    m = red[0];
    __syncthreads();

    float e = expf(x - m);

    float s = e;
    #pragma unroll
    for (int off = 32; off > 0; off >>= 1)
        s += __shfl_down(s, off);
    if (lane == 0) red[wave] = s;
    __syncthreads();
    if (t == 0) {
        float tot = 0.0f;
        #pragma unroll
        for (int i = 0; i < 8; ++i) tot += red[i];
        red[0] = tot;
    }
    __syncthreads();
    out[b * SS + t] = e / red[0];
}

extern "C" void kernel_launch(void* const* d_in, const int* in_sizes, int n_in,
                              void* d_out, int out_size, void* d_ws, size_t ws_size,
                              hipStream_t stream) {
    // inputs: hidden [2,64,1024] (unused), encoder_outputs [64,512,1024],
    //         W [1024,3072], b [1024] (unused), v [1024]
    const float* enc = (const float*)d_in[1];
    const float* W   = (const float*)d_in[2];
    const float* v   = (const float*)d_in[4];
    float* out = (float*)d_out;

    float* w2     = (float*)d_ws;         // 1024 floats
    float* scores = w2 + HID;             // 32768 floats

    wfold_kernel<<<64, 1024, 0, stream>>>(W, v, w2);

    scores_kernel<<<(BB * SS) / 4, 256, 0, stream>>>(
        (const floatx4*)enc, (const floatx4*)w2, scores);

    softmax_kernel<<<BB, 512, 0, stream>>>(scores, out);
}